// Round 11
// baseline (348.255 us; speedup 1.0000x reference)
//
#include <hip/hip_runtime.h>

#define NNODES 21844
#define ENC 256
#define HID 1024
#define ROWS 4096   // B*S = 128*32
#define NTIMES 48

typedef __attribute__((ext_vector_type(8))) short bf16x8;
typedef __attribute__((ext_vector_type(8))) unsigned short u16x8;
typedef __attribute__((ext_vector_type(4))) float f32x4;

__device__ const int g_off[8] = {0, 4, 20, 84, 340, 1364, 5460, 21844};

__device__ inline unsigned short f2bf(float f) {
  unsigned int u = __float_as_uint(f);
  u += 0x7FFF + ((u >> 16) & 1);   // round-to-nearest-even
  return (unsigned short)(u >> 16);
}

__device__ inline int depth_of(int c) {
  return (c >= 4) + (c >= 20) + (c >= 84) + (c >= 340) + (c >= 1364) + (c >= 5460);
}

// ---------------- fused preprocessing: conversions + transposes + S zeroing ----------------
__global__ __launch_bounds__(256) void prep(const float* __restrict__ prefix,
                                            const float* __restrict__ emb,
                                            const float* __restrict__ Wk,
                                            const float* __restrict__ Wt,
                                            unsigned short* __restrict__ Pb16,
                                            unsigned short* __restrict__ Eb,
                                            unsigned short* __restrict__ WkT,
                                            float* __restrict__ WtT,
                                            float* __restrict__ S) {
  int bid = blockIdx.x, tid = threadIdx.x;
  if (bid < 4096) {                          // prefix fp32 -> bf16
    int i = bid * 256 + tid;
    float4 v = reinterpret_cast<const float4*>(prefix)[i];
    ushort4 o; o.x = f2bf(v.x); o.y = f2bf(v.y); o.z = f2bf(v.z); o.w = f2bf(v.w);
    reinterpret_cast<ushort4*>(Pb16)[i] = o;
  } else if (bid < 9557) {                   // emb fp32 -> bf16
    int i = (bid - 4096) * 256 + tid;
    float4 v = reinterpret_cast<const float4*>(emb)[i];
    ushort4 o; o.x = f2bf(v.x); o.y = f2bf(v.y); o.z = f2bf(v.z); o.w = f2bf(v.w);
    reinterpret_cast<ushort4*>(Eb)[i] = o;
  } else if (bid < 10581) {                  // W_key [1024,256] -> bf16 T [256,1024]
    int i = (bid - 9557) * 256 + tid;
    int e = i >> 10, h = i & 1023;
    WkT[i] = f2bf(Wk[h * ENC + e]);
  } else if (bid < 10773) {                  // W_time [48,1024] -> f32 T [1024,48]
    int i = (bid - 10581) * 256 + tid;
    int k = i / NTIMES, c = i % NTIMES;
    WtT[i] = Wt[c * HID + k];
  } else {                                   // zero S (7*4096 floats = 7168 float4)
    int i = (bid - 10773) * 256 + tid;
    reinterpret_cast<float4*>(S)[i] = float4{0.f, 0.f, 0.f, 0.f};
  }
}

// ---------------- P2 = prefix @ W_key  (bf16 MFMA, K=1024) -> bf16 [4096,256] ----------------
__global__ __launch_bounds__(256) void p2_mfma(const unsigned short* __restrict__ Ab,
                                               const unsigned short* __restrict__ Bb,
                                               unsigned short* __restrict__ P2) {
  int lane = threadIdx.x & 63, w = threadIdx.x >> 6;
  int lr = lane & 15, lg = lane >> 4;
  int m0 = blockIdx.y * 64 + w * 16;
  int nb = blockIdx.x * 64;
  f32x4 acc[4];
#pragma unroll
  for (int n = 0; n < 4; ++n) acc[n] = f32x4{0.f, 0.f, 0.f, 0.f};
  const unsigned short* Ap = Ab + (long)(m0 + lr) * HID + lg * 8;
  for (int kk = 0; kk < 32; ++kk) {
    bf16x8 a = *reinterpret_cast<const bf16x8*>(Ap + kk * 32);
#pragma unroll
    for (int n = 0; n < 4; ++n) {
      bf16x8 b = *reinterpret_cast<const bf16x8*>(Bb + (long)(nb + n * 16 + lr) * HID + kk * 32 + lg * 8);
      acc[n] = __builtin_amdgcn_mfma_f32_16x16x32_bf16(a, b, acc[n], 0, 0, 0);
    }
  }
#pragma unroll
  for (int n = 0; n < 4; ++n)
#pragma unroll
    for (int j = 0; j < 4; ++j)
      P2[(m0 + lg * 4 + j) * ENC + nb + n * 16 + lr] = f2bf(acc[n][j]);
}

// ---------------- single GEMM pass, 128x128 tile, 2-phase double-buffered staging ----------------
// stash raw scores (final permuted layout) + per-(row,depth) exp-sum atomics
template <int BF16S>
__global__ __launch_bounds__(256) void gemm_stash(const unsigned short* __restrict__ P2,
                                                  const unsigned short* __restrict__ E,
                                                  unsigned short* __restrict__ stash,
                                                  float* __restrict__ outp,
                                                  float* __restrict__ S) {
  __shared__ unsigned short SH[2][2][128 * 64];   // [buf][A/B][128 rows x 64 k]
  int tid = threadIdx.x;
  int lane = tid & 63, w = tid >> 6;
  int lr = lane & 15, lg = lane >> 4;
  int wr = w >> 1, wc = w & 1;
  int m0 = blockIdx.x * 128, n0 = blockIdx.y * 128;
  int rr = tid >> 3, c8 = tid & 7;

  f32x4 acc[4][4];
#pragma unroll
  for (int m = 0; m < 4; ++m)
#pragma unroll
    for (int n = 0; n < 4; ++n) acc[m][n] = f32x4{0.f, 0.f, 0.f, 0.f};

#define STAGE(buf, kt)                                                                    \
  _Pragma("unroll") for (int r = 0; r < 4; ++r) {                                         \
    const unsigned short* ga = P2 + (long)(m0 + r * 32 + rr) * ENC + (kt) * 64 + c8 * 8;  \
    __builtin_amdgcn_global_load_lds(                                                     \
        (const __attribute__((address_space(1))) unsigned int*)ga,                        \
        (__attribute__((address_space(3))) unsigned int*)(&SH[buf][0][r * 2048 + w * 512]), \
        16, 0, 0);                                                                        \
    int er = n0 + r * 32 + rr;                                                            \
    if (er > NNODES - 1) er = NNODES - 1;                                                 \
    const unsigned short* gb = E + (long)er * ENC + (kt) * 64 + c8 * 8;                   \
    __builtin_amdgcn_global_load_lds(                                                     \
        (const __attribute__((address_space(1))) unsigned int*)gb,                        \
        (__attribute__((address_space(3))) unsigned int*)(&SH[buf][1][r * 2048 + w * 512]), \
        16, 0, 0);                                                                        \
  }

  STAGE(0, 0)
  __syncthreads();                     // buf0 ready
  for (int kt = 0; kt < 4; ++kt) {
    int cur = kt & 1;
    if (kt < 3) { STAGE(cur ^ 1, kt + 1) }     // prefetch flies under MFMA
    const unsigned short* As = &SH[cur][0][0];
    const unsigned short* Bs = &SH[cur][1][0];
#pragma unroll
    for (int kk = 0; kk < 2; ++kk) {
      bf16x8 a[4], b[4];
#pragma unroll
      for (int m = 0; m < 4; ++m)
        a[m] = *reinterpret_cast<const bf16x8*>(As + (wr * 64 + m * 16 + lr) * 64 + kk * 32 + lg * 8);
#pragma unroll
      for (int n = 0; n < 4; ++n)
        b[n] = *reinterpret_cast<const bf16x8*>(Bs + (wc * 64 + n * 16 + lr) * 64 + kk * 32 + lg * 8);
#pragma unroll
      for (int m = 0; m < 4; ++m)
#pragma unroll
        for (int n = 0; n < 4; ++n)
          acc[m][n] = __builtin_amdgcn_mfma_f32_16x16x32_bf16(a[m], b[n], acc[m][n], 0, 0, 0);
    }
    __syncthreads();                   // drains prefetch vmcnt + ds_reads; buf swap safe
  }
#undef STAGE

  int rbase = m0 + wr * 64 + lg * 4;
  int hstart = n0 + wc * 64;
  // write raw scores to stash (bf16) or out (fp32), final permuted layout
#pragma unroll
  for (int n = 0; n < 4; ++n) {
    int gc = hstart + n * 16 + lr;
    if (gc < NNODES) {
      int d = depth_of(gc);
      long ob = ((long)g_off[d] << 12) + (gc - g_off[d]);
      int sh = 2 * (d + 1);
#pragma unroll
      for (int m = 0; m < 4; ++m)
#pragma unroll
        for (int j = 0; j < 4; ++j) {
          int row = rbase + m * 16 + j;
          long idx = ob + ((long)row << sh);
          if (BF16S) stash[idx] = f2bf(acc[m][n][j]);
          else       outp[idx]  = acc[m][n][j];
        }
    }
  }
  // exp-sum partials (fp32 acc), 16-lane reduce, atomicAdd
  int dlo = depth_of(hstart);
  int hend = hstart + 63; if (hend > NNODES - 1) hend = NNODES - 1;
  int dhi = depth_of(hend);
  int cd[4];
#pragma unroll
  for (int n = 0; n < 4; ++n) {
    int gc = hstart + n * 16 + lr;
    cd[n] = (gc < NNODES) ? depth_of(gc) : 99;
  }
#pragma unroll
  for (int m = 0; m < 4; ++m)
#pragma unroll
    for (int n = 0; n < 4; ++n)
#pragma unroll
      for (int j = 0; j < 4; ++j) acc[m][n][j] = __expf(acc[m][n][j]);
  for (int dt = dlo; dt <= dhi; ++dt) {
#pragma unroll
    for (int m = 0; m < 4; ++m) {
      float s[4] = {0.f, 0.f, 0.f, 0.f};
#pragma unroll
      for (int n = 0; n < 4; ++n) {
        bool use = (cd[n] == dt);
#pragma unroll
        for (int j = 0; j < 4; ++j) s[j] += use ? acc[m][n][j] : 0.f;
      }
#pragma unroll
      for (int j = 0; j < 4; ++j)
#pragma unroll
        for (int o = 1; o < 16; o <<= 1) s[j] += __shfl_xor(s[j], o);
      if (lr == 0) {
#pragma unroll
        for (int j = 0; j < 4; ++j)
          atomicAdd(&S[dt * ROWS + rbase + m * 16 + j], s[j]);
      }
    }
  }
}

// ---------------- Lse = log(S) (removes TRANS dep from sub_write hot loop) ----------------
__global__ __launch_bounds__(256) void lse_log(const float* __restrict__ S,
                                               float* __restrict__ L) {
  int i = blockIdx.x * 256 + threadIdx.x;   // 7*4096 = 28672 = 112*256
  L[i] = __logf(S[i]);
}

// ---------------- pass B: out = stash - Lse[row,depth], 8-chunk MLP batching ----------------
// block = 16384 contiguous elements = 8 chunks of 2048 (depth uniform per chunk);
// all 8 stash loads issued before any use -> 128B in flight per thread.
template <int BF16S>
__global__ __launch_bounds__(256) void sub_write(const unsigned short* __restrict__ stash,
                                                 const float* __restrict__ Lse,
                                                 float* __restrict__ out) {
  int tid = threadIdx.x;
  long blk = blockIdx.x;
  long base[8];
  u16x8 u[8];
  float4 f0[8], f1[8];
#pragma unroll
  for (int i = 0; i < 8; ++i) base[i] = blk * 16384 + i * 2048 + tid * 8;
  if (BF16S) {
#pragma unroll
    for (int i = 0; i < 8; ++i) u[i] = *reinterpret_cast<const u16x8*>(stash + base[i]);
  } else {
#pragma unroll
    for (int i = 0; i < 8; ++i) {
      f0[i] = reinterpret_cast<const float4*>(out + base[i])[0];
      f1[i] = reinterpret_cast<const float4*>(out + base[i])[1];
    }
  }
#pragma unroll
  for (int i = 0; i < 8; ++i) {
    int cc = (int)blk * 8 + i;
    int d = (cc >= 8) + (cc >= 40) + (cc >= 168) + (cc >= 680) + (cc >= 2728) + (cc >= 10920);
    long bd = (d == 0) ? 0L : (d == 1) ? 16384L : (d == 2) ? 81920L : (d == 3) ? 344064L
            : (d == 4) ? 1392640L : (d == 5) ? 5586944L : 22364160L;
    long rel = base[i] - bd;
    const float* lp = Lse + d * ROWS;
    float v[8];
    if (BF16S) {
#pragma unroll
      for (int j = 0; j < 8; ++j) v[j] = __uint_as_float((unsigned)(unsigned short)u[i][j] << 16);
    } else {
      v[0] = f0[i].x; v[1] = f0[i].y; v[2] = f0[i].z; v[3] = f0[i].w;
      v[4] = f1[i].x; v[5] = f1[i].y; v[6] = f1[i].z; v[7] = f1[i].w;
    }
    float4 o0, o1;
    if (d == 0) {            // nd=4: 8 elements span rows r0, r0+1
      int r0 = (int)(rel >> 2);
      float l0 = lp[r0], l1 = lp[r0 + 1];
      o0 = float4{v[0] - l0, v[1] - l0, v[2] - l0, v[3] - l0};
      o1 = float4{v[4] - l1, v[5] - l1, v[6] - l1, v[7] - l1};
    } else {
      int row = (int)(rel >> (2 * (d + 1)));
      float l = lp[row];
      o0 = float4{v[0] - l, v[1] - l, v[2] - l, v[3] - l};
      o1 = float4{v[4] - l, v[5] - l, v[6] - l, v[7] - l};
    }
    reinterpret_cast<float4*>(out + base[i])[0] = o0;
    reinterpret_cast<float4*>(out + base[i])[1] = o1;
  }
}

// ---------------- time head: log_softmax(prefix @ W_time^T + b_time) ----------------
__global__ __launch_bounds__(256) void time_head(const float* __restrict__ prefix,
                                                 const float* __restrict__ WtT,
                                                 const float* __restrict__ bt,
                                                 float* __restrict__ out) {
  int lane = threadIdx.x & 63;
  int row = blockIdx.x * 4 + (threadIdx.x >> 6);
  const float4* pr = reinterpret_cast<const float4*>(prefix + (long)row * HID);
  float acc = -3.4e38f;
  if (lane < NTIMES) {
    float a0 = 0.f, a1 = 0.f, a2 = 0.f, a3 = 0.f;   // 4 indep partials (break FMA chain)
    for (int q = 0; q < HID / 4; ++q) {
      float4 pv = pr[q];
      const float* wrow = WtT + q * 4 * NTIMES;
      a0 += pv.x * wrow[lane];
      a1 += pv.y * wrow[NTIMES + lane];
      a2 += pv.z * wrow[2 * NTIMES + lane];
      a3 += pv.w * wrow[3 * NTIMES + lane];
    }
    acc = (a0 + a1) + (a2 + a3) + bt[lane];
  }
  float m = acc;
#pragma unroll
  for (int d = 32; d; d >>= 1) m = fmaxf(m, __shfl_xor(m, d));
  float e = (lane < NTIMES) ? __expf(acc - m) : 0.f;
  float s = e;
#pragma unroll
  for (int d = 32; d; d >>= 1) s += __shfl_xor(s, d);
  if (lane < NTIMES) out[89473024 + row * NTIMES + lane] = acc - m - __logf(s);
}

extern "C" void kernel_launch(void* const* d_in, const int* in_sizes, int n_in,
                              void* d_out, int out_size, void* d_ws, size_t ws_size,
                              hipStream_t stream) {
  const float* prefix = (const float*)d_in[0];  // [128,32,1024]
  const float* emb    = (const float*)d_in[1];  // [21844,256]
  const float* Wk     = (const float*)d_in[2];  // [1024,256]
  const float* Wt     = (const float*)d_in[4];  // [48,1024]
  const float* bt     = (const float*)d_in[5];  // [48]
  float* out = (float*)d_out;
  char* ws = (char*)d_ws;

  // workspace layout (16B aligned)
  unsigned short* P2    = (unsigned short*)(ws + 0);          // 4096*256 bf16
  unsigned short* Eb    = (unsigned short*)(ws + 2097152);    // 21844*256 bf16
  unsigned short* WkT   = (unsigned short*)(ws + 13281280);   // 256*1024 bf16
  unsigned short* Pb16  = (unsigned short*)(ws + 13805568);   // 4096*1024 bf16
  float*          WtT   = (float*)(ws + 22194176);            // 1024*48 f32
  float*          S     = (float*)(ws + 22390784);            // 7*4096 f32
  float*          Lse   = (float*)(ws + 22505472);            // 7*4096 f32
  unsigned short* stash = (unsigned short*)(ws + 22620160);   // 89473024 bf16
  const size_t WS_NEED_STASH = 22620160UL + 178946048UL;      // ~201.6 MB

  bool big = ws_size >= WS_NEED_STASH;

  prep<<<10801, 256, 0, stream>>>(prefix, emb, Wk, Wt, Pb16, Eb, WkT, WtT, S);

  p2_mfma<<<dim3(4, 64), 256, 0, stream>>>(Pb16, WkT, P2);

  if (big) {
    gemm_stash<1><<<dim3(32, 171), 256, 0, stream>>>(P2, Eb, stash, out, S);
    lse_log<<<112, 256, 0, stream>>>(S, Lse);
    sub_write<1><<<5461, 256, 0, stream>>>(stash, Lse, out);
  } else {
    gemm_stash<0><<<dim3(32, 171), 256, 0, stream>>>(P2, Eb, stash, out, S);
    lse_log<<<112, 256, 0, stream>>>(S, Lse);
    sub_write<0><<<5461, 256, 0, stream>>>(stash, Lse, out);
  }

  time_head<<<1024, 256, 0, stream>>>(prefix, WtT, bt, out);
}

// Round 12
// 341.999 us; speedup vs baseline: 1.0183x; 1.0183x over previous
//
#include <hip/hip_runtime.h>

#define NNODES 21844
#define ENC 256
#define HID 1024
#define ROWS 4096   // B*S = 128*32
#define NTIMES 48

typedef __attribute__((ext_vector_type(8))) short bf16x8;
typedef __attribute__((ext_vector_type(8))) unsigned short u16x8;
typedef __attribute__((ext_vector_type(4))) unsigned short u16x4;
typedef __attribute__((ext_vector_type(4))) float f32x4;

__device__ const int g_off[8] = {0, 4, 20, 84, 340, 1364, 5460, 21844};

__device__ inline unsigned short f2bf(float f) {
  unsigned int u = __float_as_uint(f);
  u += 0x7FFF + ((u >> 16) & 1);   // round-to-nearest-even
  return (unsigned short)(u >> 16);
}

__device__ inline int depth_of(int c) {
  return (c >= 4) + (c >= 20) + (c >= 84) + (c >= 340) + (c >= 1364) + (c >= 5460);
}

// ---------------- fused preprocessing: conversions + transposes + S zeroing ----------------
__global__ __launch_bounds__(256) void prep(const float* __restrict__ prefix,
                                            const float* __restrict__ emb,
                                            const float* __restrict__ Wk,
                                            const float* __restrict__ Wt,
                                            unsigned short* __restrict__ Pb16,
                                            unsigned short* __restrict__ Eb,
                                            unsigned short* __restrict__ WkT,
                                            float* __restrict__ WtT,
                                            float* __restrict__ S) {
  int bid = blockIdx.x, tid = threadIdx.x;
  if (bid < 4096) {                          // prefix fp32 -> bf16
    int i = bid * 256 + tid;
    float4 v = reinterpret_cast<const float4*>(prefix)[i];
    ushort4 o; o.x = f2bf(v.x); o.y = f2bf(v.y); o.z = f2bf(v.z); o.w = f2bf(v.w);
    reinterpret_cast<ushort4*>(Pb16)[i] = o;
  } else if (bid < 9557) {                   // emb fp32 -> bf16
    int i = (bid - 4096) * 256 + tid;
    float4 v = reinterpret_cast<const float4*>(emb)[i];
    ushort4 o; o.x = f2bf(v.x); o.y = f2bf(v.y); o.z = f2bf(v.z); o.w = f2bf(v.w);
    reinterpret_cast<ushort4*>(Eb)[i] = o;
  } else if (bid < 10581) {                  // W_key [1024,256] -> bf16 T [256,1024]
    int i = (bid - 9557) * 256 + tid;
    int e = i >> 10, h = i & 1023;
    WkT[i] = f2bf(Wk[h * ENC + e]);
  } else if (bid < 10773) {                  // W_time [48,1024] -> f32 T [1024,48]
    int i = (bid - 10581) * 256 + tid;
    int k = i / NTIMES, c = i % NTIMES;
    WtT[i] = Wt[c * HID + k];
  } else {                                   // zero S (7*4096 floats = 7168 float4)
    int i = (bid - 10773) * 256 + tid;
    reinterpret_cast<float4*>(S)[i] = float4{0.f, 0.f, 0.f, 0.f};
  }
}

// ---------------- P2 = prefix @ W_key  (bf16 MFMA, K=1024) -> bf16 [4096,256] ----------------
__global__ __launch_bounds__(256) void p2_mfma(const unsigned short* __restrict__ Ab,
                                               const unsigned short* __restrict__ Bb,
                                               unsigned short* __restrict__ P2) {
  int lane = threadIdx.x & 63, w = threadIdx.x >> 6;
  int lr = lane & 15, lg = lane >> 4;
  int m0 = blockIdx.y * 64 + w * 16;
  int nb = blockIdx.x * 64;
  f32x4 acc[4];
#pragma unroll
  for (int n = 0; n < 4; ++n) acc[n] = f32x4{0.f, 0.f, 0.f, 0.f};
  const unsigned short* Ap = Ab + (long)(m0 + lr) * HID + lg * 8;
  for (int kk = 0; kk < 32; ++kk) {
    bf16x8 a = *reinterpret_cast<const bf16x8*>(Ap + kk * 32);
#pragma unroll
    for (int n = 0; n < 4; ++n) {
      bf16x8 b = *reinterpret_cast<const bf16x8*>(Bb + (long)(nb + n * 16 + lr) * HID + kk * 32 + lg * 8);
      acc[n] = __builtin_amdgcn_mfma_f32_16x16x32_bf16(a, b, acc[n], 0, 0, 0);
    }
  }
#pragma unroll
  for (int n = 0; n < 4; ++n)
#pragma unroll
    for (int j = 0; j < 4; ++j)
      P2[(m0 + lg * 4 + j) * ENC + nb + n * 16 + lr] = f2bf(acc[n][j]);
}

// ---------------- single GEMM pass, 128x128 tile, 2-phase double-buffered staging ----------------
// stash raw scores (final permuted layout) + per-(row,depth) exp-sum atomics
template <int BF16S>
__global__ __launch_bounds__(256) void gemm_stash(const unsigned short* __restrict__ P2,
                                                  const unsigned short* __restrict__ E,
                                                  unsigned short* __restrict__ stash,
                                                  float* __restrict__ outp,
                                                  float* __restrict__ S) {
  __shared__ unsigned short SH[2][2][128 * 64];   // [buf][A/B][128 rows x 64 k]
  int tid = threadIdx.x;
  int lane = tid & 63, w = tid >> 6;
  int lr = lane & 15, lg = lane >> 4;
  int wr = w >> 1, wc = w & 1;
  int m0 = blockIdx.x * 128, n0 = blockIdx.y * 128;
  int rr = tid >> 3, c8 = tid & 7;

  f32x4 acc[4][4];
#pragma unroll
  for (int m = 0; m < 4; ++m)
#pragma unroll
    for (int n = 0; n < 4; ++n) acc[m][n] = f32x4{0.f, 0.f, 0.f, 0.f};

#define STAGE(buf, kt)                                                                    \
  _Pragma("unroll") for (int r = 0; r < 4; ++r) {                                         \
    const unsigned short* ga = P2 + (long)(m0 + r * 32 + rr) * ENC + (kt) * 64 + c8 * 8;  \
    __builtin_amdgcn_global_load_lds(                                                     \
        (const __attribute__((address_space(1))) unsigned int*)ga,                        \
        (__attribute__((address_space(3))) unsigned int*)(&SH[buf][0][r * 2048 + w * 512]), \
        16, 0, 0);                                                                        \
    int er = n0 + r * 32 + rr;                                                            \
    if (er > NNODES - 1) er = NNODES - 1;                                                 \
    const unsigned short* gb = E + (long)er * ENC + (kt) * 64 + c8 * 8;                   \
    __builtin_amdgcn_global_load_lds(                                                     \
        (const __attribute__((address_space(1))) unsigned int*)gb,                        \
        (__attribute__((address_space(3))) unsigned int*)(&SH[buf][1][r * 2048 + w * 512]), \
        16, 0, 0);                                                                        \
  }

  STAGE(0, 0)
  __syncthreads();                     // buf0 ready
  for (int kt = 0; kt < 4; ++kt) {
    int cur = kt & 1;
    if (kt < 3) { STAGE(cur ^ 1, kt + 1) }     // prefetch flies under MFMA
    const unsigned short* As = &SH[cur][0][0];
    const unsigned short* Bs = &SH[cur][1][0];
#pragma unroll
    for (int kk = 0; kk < 2; ++kk) {
      bf16x8 a[4], b[4];
#pragma unroll
      for (int m = 0; m < 4; ++m)
        a[m] = *reinterpret_cast<const bf16x8*>(As + (wr * 64 + m * 16 + lr) * 64 + kk * 32 + lg * 8);
#pragma unroll
      for (int n = 0; n < 4; ++n)
        b[n] = *reinterpret_cast<const bf16x8*>(Bs + (wc * 64 + n * 16 + lr) * 64 + kk * 32 + lg * 8);
#pragma unroll
      for (int m = 0; m < 4; ++m)
#pragma unroll
        for (int n = 0; n < 4; ++n)
          acc[m][n] = __builtin_amdgcn_mfma_f32_16x16x32_bf16(a[m], b[n], acc[m][n], 0, 0, 0);
    }
    __syncthreads();                   // drains prefetch vmcnt + ds_reads; buf swap safe
  }
#undef STAGE

  int rbase = m0 + wr * 64 + lg * 4;
  int hstart = n0 + wc * 64;
  // write raw scores to stash (bf16) or out (fp32), final permuted layout
#pragma unroll
  for (int n = 0; n < 4; ++n) {
    int gc = hstart + n * 16 + lr;
    if (gc < NNODES) {
      int d = depth_of(gc);
      long ob = ((long)g_off[d] << 12) + (gc - g_off[d]);
      int sh = 2 * (d + 1);
#pragma unroll
      for (int m = 0; m < 4; ++m)
#pragma unroll
        for (int j = 0; j < 4; ++j) {
          int row = rbase + m * 16 + j;
          long idx = ob + ((long)row << sh);
          if (BF16S) stash[idx] = f2bf(acc[m][n][j]);
          else       outp[idx]  = acc[m][n][j];
        }
    }
  }
  // exp-sum partials (fp32 acc), 16-lane reduce, atomicAdd
  int dlo = depth_of(hstart);
  int hend = hstart + 63; if (hend > NNODES - 1) hend = NNODES - 1;
  int dhi = depth_of(hend);
  int cd[4];
#pragma unroll
  for (int n = 0; n < 4; ++n) {
    int gc = hstart + n * 16 + lr;
    cd[n] = (gc < NNODES) ? depth_of(gc) : 99;
  }
#pragma unroll
  for (int m = 0; m < 4; ++m)
#pragma unroll
    for (int n = 0; n < 4; ++n)
#pragma unroll
      for (int j = 0; j < 4; ++j) acc[m][n][j] = __expf(acc[m][n][j]);
  for (int dt = dlo; dt <= dhi; ++dt) {
#pragma unroll
    for (int m = 0; m < 4; ++m) {
      float s[4] = {0.f, 0.f, 0.f, 0.f};
#pragma unroll
      for (int n = 0; n < 4; ++n) {
        bool use = (cd[n] == dt);
#pragma unroll
        for (int j = 0; j < 4; ++j) s[j] += use ? acc[m][n][j] : 0.f;
      }
#pragma unroll
      for (int j = 0; j < 4; ++j)
#pragma unroll
        for (int o = 1; o < 16; o <<= 1) s[j] += __shfl_xor(s[j], o);
      if (lr == 0) {
#pragma unroll
        for (int j = 0; j < 4; ++j)
          atomicAdd(&S[dt * ROWS + rbase + m * 16 + j], s[j]);
      }
    }
  }
}

// ---------------- pass B (bf16 stash): persistent LDS-staged bulk streaming ----------------
// 2048 blocks; per iter: async-stage 16KB stash -> LDS (read burst), barrier,
// then 32KB perfectly-coalesced fp32 store burst. log(S) folded in.
// 89473024 elems = 10922 iters x 8192.
__global__ __launch_bounds__(256) void sub_write_lds(const unsigned short* __restrict__ stash,
                                                     const float* __restrict__ S,
                                                     float* __restrict__ out) {
  __shared__ unsigned short L[8192];   // 16 KB -> 8 blocks/CU
  int tid = threadIdx.x;
  for (int it = blockIdx.x; it < 10922; it += 2048) {
    long ibase = (long)it * 8192;
    int itc = it * 4;                  // first 2048-elem chunk index of this iter
    // stage: 4 x (256 threads x 16B) async read bursts
#pragma unroll
    for (int s = 0; s < 4; ++s) {
      const unsigned short* src = stash + ibase + s * 2048 + tid * 8;
      __builtin_amdgcn_global_load_lds(
          (const __attribute__((address_space(1))) unsigned int*)src,
          (__attribute__((address_space(3))) unsigned int*)(&L[s * 2048 + (tid >> 6) * 512]),
          16, 0, 0);
    }
    __syncthreads();                   // drains vmcnt; LDS ready
    // store burst: 8 x float4 per thread, 1KB contiguous per wave-instruction
#pragma unroll
    for (int j = 0; j < 8; ++j) {
      int fidx = j * 256 + tid;        // float4 index within iter [0,2048)
      long eidx = ibase + (long)fidx * 4;
      int cc = itc + (j >> 1);         // chunk uniform per j
      int d = (cc >= 8) + (cc >= 40) + (cc >= 168) + (cc >= 680) + (cc >= 2728) + (cc >= 10920);
      long bd = (d == 0) ? 0L : (d == 1) ? 16384L : (d == 2) ? 81920L : (d == 3) ? 344064L
              : (d == 4) ? 1392640L : (d == 5) ? 5586944L : 22364160L;
      int row = (int)((eidx - bd) >> (2 * (d + 1)));
      float l = __logf(S[d * ROWS + row]);
      u16x4 u = *reinterpret_cast<const u16x4*>(&L[fidx * 4]);
      float4 o;
      o.x = __uint_as_float((unsigned)(unsigned short)u[0] << 16) - l;
      o.y = __uint_as_float((unsigned)(unsigned short)u[1] << 16) - l;
      o.z = __uint_as_float((unsigned)(unsigned short)u[2] << 16) - l;
      o.w = __uint_as_float((unsigned)(unsigned short)u[3] << 16) - l;
      *reinterpret_cast<float4*>(out + eidx) = o;
    }
    __syncthreads();                   // L reuse safe next iter
  }
}

// ---------------- pass B fallback (fp32 in out): in-place subtract ----------------
__global__ __launch_bounds__(256) void sub_write_inplace(const float* __restrict__ S,
                                                         float* __restrict__ out) {
  int tid = threadIdx.x;
  long blk = blockIdx.x;
#pragma unroll
  for (int i = 0; i < 8; ++i) {
    long base = blk * 16384 + i * 2048 + tid * 8;
    int cc = (int)blk * 8 + i;
    int d = (cc >= 8) + (cc >= 40) + (cc >= 168) + (cc >= 680) + (cc >= 2728) + (cc >= 10920);
    long bd = (d == 0) ? 0L : (d == 1) ? 16384L : (d == 2) ? 81920L : (d == 3) ? 344064L
            : (d == 4) ? 1392640L : (d == 5) ? 5586944L : 22364160L;
    long rel = base - bd;
    const float* sp = S + d * ROWS;
    float4 a = reinterpret_cast<const float4*>(out + base)[0];
    float4 b = reinterpret_cast<const float4*>(out + base)[1];
    float4 o0, o1;
    if (d == 0) {
      int r0 = (int)(rel >> 2);
      float l0 = __logf(sp[r0]), l1 = __logf(sp[r0 + 1]);
      o0 = float4{a.x - l0, a.y - l0, a.z - l0, a.w - l0};
      o1 = float4{b.x - l1, b.y - l1, b.z - l1, b.w - l1};
    } else {
      int row = (int)(rel >> (2 * (d + 1)));
      float l = __logf(sp[row]);
      o0 = float4{a.x - l, a.y - l, a.z - l, a.w - l};
      o1 = float4{b.x - l, b.y - l, b.z - l, b.w - l};
    }
    reinterpret_cast<float4*>(out + base)[0] = o0;
    reinterpret_cast<float4*>(out + base)[1] = o1;
  }
}

// ---------------- time head: log_softmax(prefix @ W_time^T + b_time) ----------------
__global__ __launch_bounds__(256) void time_head(const float* __restrict__ prefix,
                                                 const float* __restrict__ WtT,
                                                 const float* __restrict__ bt,
                                                 float* __restrict__ out) {
  int lane = threadIdx.x & 63;
  int row = blockIdx.x * 4 + (threadIdx.x >> 6);
  const float4* pr = reinterpret_cast<const float4*>(prefix + (long)row * HID);
  float acc = -3.4e38f;
  if (lane < NTIMES) {
    float a0 = 0.f, a1 = 0.f, a2 = 0.f, a3 = 0.f;   // 4 indep partials (break FMA chain)
    for (int q = 0; q < HID / 4; ++q) {
      float4 pv = pr[q];
      const float* wrow = WtT + q * 4 * NTIMES;
      a0 += pv.x * wrow[lane];
      a1 += pv.y * wrow[NTIMES + lane];
      a2 += pv.z * wrow[2 * NTIMES + lane];
      a3 += pv.w * wrow[3 * NTIMES + lane];
    }
    acc = (a0 + a1) + (a2 + a3) + bt[lane];
  }
  float m = acc;
#pragma unroll
  for (int d = 32; d; d >>= 1) m = fmaxf(m, __shfl_xor(m, d));
  float e = (lane < NTIMES) ? __expf(acc - m) : 0.f;
  float s = e;
#pragma unroll
  for (int d = 32; d; d >>= 1) s += __shfl_xor(s, d);
  if (lane < NTIMES) out[89473024 + row * NTIMES + lane] = acc - m - __logf(s);
}

extern "C" void kernel_launch(void* const* d_in, const int* in_sizes, int n_in,
                              void* d_out, int out_size, void* d_ws, size_t ws_size,
                              hipStream_t stream) {
  const float* prefix = (const float*)d_in[0];  // [128,32,1024]
  const float* emb    = (const float*)d_in[1];  // [21844,256]
  const float* Wk     = (const float*)d_in[2];  // [1024,256]
  const float* Wt     = (const float*)d_in[4];  // [48,1024]
  const float* bt     = (const float*)d_in[5];  // [48]
  float* out = (float*)d_out;
  char* ws = (char*)d_ws;

  // workspace layout (16B aligned)
  unsigned short* P2    = (unsigned short*)(ws + 0);          // 4096*256 bf16
  unsigned short* Eb    = (unsigned short*)(ws + 2097152);    // 21844*256 bf16
  unsigned short* WkT   = (unsigned short*)(ws + 13281280);   // 256*1024 bf16
  unsigned short* Pb16  = (unsigned short*)(ws + 13805568);   // 4096*1024 bf16
  float*          WtT   = (float*)(ws + 22194176);            // 1024*48 f32
  float*          S     = (float*)(ws + 22390784);            // 7*4096 f32
  unsigned short* stash = (unsigned short*)(ws + 22620160);   // 89473024 bf16
  const size_t WS_NEED_STASH = 22620160UL + 178946048UL;      // ~201.6 MB

  bool big = ws_size >= WS_NEED_STASH;

  prep<<<10801, 256, 0, stream>>>(prefix, emb, Wk, Wt, Pb16, Eb, WkT, WtT, S);

  p2_mfma<<<dim3(4, 64), 256, 0, stream>>>(Pb16, WkT, P2);

  if (big) {
    gemm_stash<1><<<dim3(32, 171), 256, 0, stream>>>(P2, Eb, stash, out, S);
    sub_write_lds<<<2048, 256, 0, stream>>>(stash, S, out);
  } else {
    gemm_stash<0><<<dim3(32, 171), 256, 0, stream>>>(P2, Eb, stash, out, S);
    sub_write_inplace<<<5461, 256, 0, stream>>>(S, out);
  }

  time_head<<<1024, 256, 0, stream>>>(prefix, WtT, bt, out);
}